// Round 4
// baseline (235.513 us; speedup 1.0000x reference)
//
#include <hip/hip_runtime.h>
#include <hip/hip_bf16.h>
#include <math.h>

#define B 2
#define T 2048
#define C 1024
#define NH 16
#define NKV 4
#define HD 64
#define M 64
#define GC 32
#define S_TOT (M + T)   // 2112
#define EPS 1e-6f

using bf16x8  = __attribute__((ext_vector_type(8))) __bf16;
using f32x4   = __attribute__((ext_vector_type(4))) float;
using ushort8 = __attribute__((ext_vector_type(8))) unsigned short;
using ushort4v= __attribute__((ext_vector_type(4))) unsigned short;

typedef __attribute__((address_space(1))) const void GV;
typedef __attribute__((address_space(3))) void LV;

__device__ inline unsigned short f2bf(float f) {
    __bf16 h = (__bf16)f;
    return __builtin_bit_cast(unsigned short, h);
}
__device__ inline float bf2f(unsigned short u) {
    unsigned int x = (unsigned int)u << 16;
    return __builtin_bit_cast(float, x);
}
__device__ inline float wave_sum(float v) {
    #pragma unroll
    for (int off = 32; off; off >>= 1) v += __shfl_xor(v, off, 64);
    return v;
}

// ------------------------------------------------------------ fp32 -> bf16
__global__ __launch_bounds__(256) void cast_kernel(
    const float* __restrict__ src, unsigned short* __restrict__ dst, int n4)
{
    int i = blockIdx.x * 256 + threadIdx.x;
    if (i < n4) {
        float4 v = ((const float4*)src)[i];
        ushort4v o;
        o.x = f2bf(v.x); o.y = f2bf(v.y); o.z = f2bf(v.z); o.w = f2bf(v.w);
        ((ushort4v*)dst)[i] = o;
    }
}

// ------------------------------------------------------- bf16 MFMA GEMM (m97)
// C[m,n] = sum_k A[m,k]*Bt[n,k]; 128x128 tile, BK=64, 4 waves 2x2,
// global_load_lds width-16 staging into linear LDS [128][64].
template<bool OUT_BF16>
__global__ __launch_bounds__(256) void gemm_bf16(
    const unsigned short* __restrict__ A, const unsigned short* __restrict__ Bt,
    void* __restrict__ Cc, int Nn, int Kk)
{
    __shared__ unsigned short As[128 * 64];
    __shared__ unsigned short Bs[128 * 64];
    const int tid = threadIdx.x;
    const int w = tid >> 6, lane = tid & 63, lx = lane & 15, hi = lane >> 4;
    const int wr = w >> 1, wc = w & 1;
    const int m0 = blockIdx.y * 128, n0 = blockIdx.x * 128;
    const int lrow = lane >> 3;            // 0..7 within chunk
    const int lcol = (lane & 7) * 8;       // ushort col 0..56

    f32x4 acc[4][4];
    #pragma unroll
    for (int mi = 0; mi < 4; ++mi)
        #pragma unroll
        for (int ni = 0; ni < 4; ++ni) acc[mi][ni] = (f32x4){0.f, 0.f, 0.f, 0.f};

    for (int k0 = 0; k0 < Kk; k0 += 64) {
        #pragma unroll
        for (int p = 0; p < 4; ++p) {
            const int chunk = w * 4 + p;           // 0..15, 8 rows each
            const int row = chunk * 8 + lrow;
            __builtin_amdgcn_global_load_lds(
                (GV*)(A + (size_t)(m0 + row) * Kk + k0 + lcol),
                (LV*)(As + chunk * 512), 16, 0, 0);
            __builtin_amdgcn_global_load_lds(
                (GV*)(Bt + (size_t)(n0 + row) * Kk + k0 + lcol),
                (LV*)(Bs + chunk * 512), 16, 0, 0);
        }
        __syncthreads();
        #pragma unroll
        for (int kk = 0; kk < 2; ++kk) {
            bf16x8 af[4], bfr[4];
            #pragma unroll
            for (int mi = 0; mi < 4; ++mi)
                af[mi] = *(const bf16x8*)&As[(wr * 64 + mi * 16 + lx) * 64 + kk * 32 + hi * 8];
            #pragma unroll
            for (int ni = 0; ni < 4; ++ni)
                bfr[ni] = *(const bf16x8*)&Bs[(wc * 64 + ni * 16 + lx) * 64 + kk * 32 + hi * 8];
            #pragma unroll
            for (int mi = 0; mi < 4; ++mi)
                #pragma unroll
                for (int ni = 0; ni < 4; ++ni)
                    acc[mi][ni] = __builtin_amdgcn_mfma_f32_16x16x32_bf16(
                        af[mi], bfr[ni], acc[mi][ni], 0, 0, 0);
        }
        __syncthreads();
    }
    #pragma unroll
    for (int mi = 0; mi < 4; ++mi)
        #pragma unroll
        for (int ni = 0; ni < 4; ++ni)
            #pragma unroll
            for (int r = 0; r < 4; ++r) {
                size_t idx = (size_t)(m0 + wr * 64 + mi * 16 + hi * 4 + r) * Nn
                           + n0 + wc * 64 + ni * 16 + lx;
                if constexpr (OUT_BF16) ((unsigned short*)Cc)[idx] = f2bf(acc[mi][ni][r]);
                else                    ((float*)Cc)[idx] = acc[mi][ni][r];
            }
}

// ------------------------------------------------- gate + RoPE + RMS fusion
__global__ __launch_bounds__(256) void fuse_kernel(
    const float* __restrict__ x, const float* __restrict__ ve,
    const float* __restrict__ cosb, const float* __restrict__ sinb,
    const float* __restrict__ Wg, const unsigned short* __restrict__ qkv,
    unsigned short* __restrict__ qh, unsigned short* __restrict__ kfull,
    unsigned short* __restrict__ vfull)
{
    const int bt = blockIdx.x;
    const int b = bt >> 11, t = bt & (T - 1);
    const int w = threadIdx.x >> 6, l = threadIdx.x & 63, i = l & 31;
    const float c = cosb[t * 32 + i];
    const float s = sinb[t * 32 + i];
    const unsigned short* row = qkv + (size_t)bt * 1536;

    #pragma unroll
    for (int hq = 0; hq < 4; ++hq) {
        const int h = w + hq * 4;
        float x1 = bf2f(row[h * 64 + i]);
        float x2 = bf2f(row[h * 64 + i + 32]);
        float val = (l < 32) ? (x1 * c - x2 * s) : (x1 * s + x2 * c);
        float ss = wave_sum(val * val);
        float scale = rsqrtf(ss * (1.f / 64.f) + EPS) * 1.2f;
        qh[((size_t)(b * NH + h) * T + t) * 64 + l] = f2bf(val * scale);
    }
    {
        float x1 = bf2f(row[1024 + w * 64 + i]);
        float x2 = bf2f(row[1024 + w * 64 + i + 32]);
        float val = (l < 32) ? (x1 * c - x2 * s) : (x1 * s + x2 * c);
        float ss = wave_sum(val * val);
        float scale = rsqrtf(ss * (1.f / 64.f) + EPS) * 1.2f;
        kfull[((size_t)(b * NKV + w) * S_TOT + M + t) * 64 + l] = f2bf(val * scale);
    }
    {
        const float* xr = x + (size_t)bt * 1024;
        float g = 0.f;
        #pragma unroll
        for (int gi = 0; gi < GC; ++gi) g += xr[gi] * Wg[w * GC + gi];
        g = 3.f / (1.f + __expf(-g));
        float vv = bf2f(row[1280 + w * 64 + l]) + g * ve[(size_t)bt * 256 + w * 64 + l];
        vfull[((size_t)(b * NKV + w) * S_TOT + M + t) * 64 + l] = f2bf(vv);
    }
}

// ------------------------------------------------------- memory token prep
__global__ __launch_bounds__(256) void mem_kernel(
    const float* __restrict__ mem_k, const float* __restrict__ mem_v,
    const float* __restrict__ vscal,
    unsigned short* __restrict__ kfull, unsigned short* __restrict__ vfull)
{
    const int bm = blockIdx.x;
    const int b = bm >> 6, mr = bm & 63;
    const int w = threadIdx.x >> 6, l = threadIdx.x & 63;
    const size_t src = ((size_t)mr * NKV + w) * HD + l;
    float kvv = mem_k[src];
    float ss = wave_sum(kvv * kvv);
    float scale = rsqrtf(ss * (1.f / 64.f) + EPS) * 1.2f;
    const size_t dst = ((size_t)(b * NKV + w) * S_TOT + mr) * 64 + l;
    kfull[dst] = f2bf(kvv * scale);
    vfull[dst] = f2bf(mem_v[src] * vscal[0]);
}

// --------------------------------------------------------- MFMA flash attn v3
// block = (tt, h, b), 4 waves; wave w owns q rows t0+16w..+15.
// K fragments read direct from global (L2-resident); V reg-prefetched (T14)
// and written transposed into double-buffered LDS -> 1 barrier per tile.
__global__ __launch_bounds__(256) void attn_kernel(
    const unsigned short* __restrict__ qh, const unsigned short* __restrict__ kf,
    const unsigned short* __restrict__ vf, unsigned short* __restrict__ y)
{
    __shared__ unsigned short Vt[2][64][72];
    __shared__ unsigned short Ps[64][72];
    const int tt = blockIdx.x, h = blockIdx.y, b = blockIdx.z;
    const int kv = h >> 2, t0 = tt * 64;
    const int tid = threadIdx.x, w = tid >> 6, lane = tid & 63;
    const int lx = lane & 15, hi = lane >> 4;

    bf16x8 aq[2];
    {
        const unsigned short* qp = qh + ((size_t)(b * NH + h) * T + t0 + 16 * w + lx) * 64;
        aq[0] = *(const bf16x8*)&qp[hi * 8];
        aq[1] = *(const bf16x8*)&qp[32 + hi * 8];
    }
    f32x4 o_acc[4];
    #pragma unroll
    for (int dt = 0; dt < 4; ++dt) o_acc[dt] = (f32x4){0.f, 0.f, 0.f, 0.f};
    float m_r[4], l_r[4];
    #pragma unroll
    for (int r = 0; r < 4; ++r) { m_r[r] = -INFINITY; l_r[r] = 0.f; }

    const unsigned short* kbase = kf + (size_t)(b * NKV + kv) * S_TOT * 64;
    const unsigned short* vbase = vf + (size_t)(b * NKV + kv) * S_TOT * 64;

    const int nst = tt + 2;
    // prefetch V tile 0 into regs
    ushort8 vn[2];
    {
        const unsigned short* vp = vbase + (size_t)lane * 64;
        vn[0] = *(const ushort8*)&vp[w * 8];
        vn[1] = *(const ushort8*)&vp[(4 + w) * 8];
    }
    int cur = 0;
    for (int st = 0; st < nst; ++st) {
        const int s0 = st * 64;
        // write prefetched V transposed into Vt[cur]
        #pragma unroll
        for (int p = 0; p < 2; ++p) {
            const int kb = p * 4 + w;
            #pragma unroll
            for (int j = 0; j < 8; ++j) Vt[cur][kb * 8 + j][lane] = (unsigned short)vn[p][j];
        }
        __syncthreads();
        // prefetch next V tile (hidden under this tile's compute)
        if (st + 1 < nst) {
            const unsigned short* vp = vbase + (size_t)(s0 + 64 + lane) * 64;
            vn[0] = *(const ushort8*)&vp[w * 8];
            vn[1] = *(const ushort8*)&vp[(4 + w) * 8];
        }
        // S = Q K^T, K fragments direct from global
        const unsigned short* kp = kbase + (size_t)s0 * 64;
        bf16x8 kb0[4], kb1[4];
        #pragma unroll
        for (int nt = 0; nt < 4; ++nt) {
            kb0[nt] = *(const bf16x8*)&kp[(size_t)(nt * 16 + lx) * 64 + hi * 8];
            kb1[nt] = *(const bf16x8*)&kp[(size_t)(nt * 16 + lx) * 64 + 32 + hi * 8];
        }
        f32x4 s_acc[4];
        #pragma unroll
        for (int nt = 0; nt < 4; ++nt) s_acc[nt] = (f32x4){0.f, 0.f, 0.f, 0.f};
        #pragma unroll
        for (int nt = 0; nt < 4; ++nt) {
            s_acc[nt] = __builtin_amdgcn_mfma_f32_16x16x32_bf16(aq[0], kb0[nt], s_acc[nt], 0, 0, 0);
            s_acc[nt] = __builtin_amdgcn_mfma_f32_16x16x32_bf16(aq[1], kb1[nt], s_acc[nt], 0, 0, 0);
        }
        // scale + causal mask (diag tile only)
        const bool diag = (st == nst - 1);
        #pragma unroll
        for (int nt = 0; nt < 4; ++nt)
            #pragma unroll
            for (int r = 0; r < 4; ++r) {
                float v = s_acc[nt][r] * 0.125f;
                if (diag && (nt * 16 + lx) > (16 * w + hi * 4 + r)) v = -INFINITY;
                s_acc[nt][r] = v;
            }
        // row max (16-lane butterfly)
        float mx[4];
        #pragma unroll
        for (int r = 0; r < 4; ++r)
            mx[r] = fmaxf(fmaxf(s_acc[0][r], s_acc[1][r]), fmaxf(s_acc[2][r], s_acc[3][r]));
        #pragma unroll
        for (int off = 1; off < 16; off <<= 1)
            #pragma unroll
            for (int r = 0; r < 4; ++r) mx[r] = fmaxf(mx[r], __shfl_xor(mx[r], off, 64));
        float resc[4];
        #pragma unroll
        for (int r = 0; r < 4; ++r) {
            float mn = fmaxf(m_r[r], mx[r]);
            resc[r] = __expf(m_r[r] - mn);
            m_r[r] = mn;
        }
        // P = exp(S - m) -> bf16 LDS (per-wave private rows)
        #pragma unroll
        for (int r = 0; r < 4; ++r) {
            float ps = 0.f;
            #pragma unroll
            for (int nt = 0; nt < 4; ++nt) {
                float p = __expf(s_acc[nt][r] - m_r[r]);
                ps += p;
                Ps[16 * w + hi * 4 + r][nt * 16 + lx] = f2bf(p);
            }
            l_r[r] = l_r[r] * resc[r] + ps;
        }
        #pragma unroll
        for (int dt = 0; dt < 4; ++dt)
            #pragma unroll
            for (int r = 0; r < 4; ++r) o_acc[dt][r] *= resc[r];
        // O += P V
        #pragma unroll
        for (int kk = 0; kk < 2; ++kk) {
            bf16x8 pa = *(const bf16x8*)&Ps[16 * w + lx][kk * 32 + hi * 8];
            #pragma unroll
            for (int dt = 0; dt < 4; ++dt) {
                bf16x8 vb = *(const bf16x8*)&Vt[cur][dt * 16 + lx][kk * 32 + hi * 8];
                o_acc[dt] = __builtin_amdgcn_mfma_f32_16x16x32_bf16(pa, vb, o_acc[dt], 0, 0, 0);
            }
        }
        cur ^= 1;
    }

    float lt[4];
    #pragma unroll
    for (int r = 0; r < 4; ++r) {
        float v = l_r[r];
        #pragma unroll
        for (int off = 1; off < 16; off <<= 1) v += __shfl_xor(v, off, 64);
        lt[r] = 1.f / v;
    }
    #pragma unroll
    for (int dt = 0; dt < 4; ++dt)
        #pragma unroll
        for (int r = 0; r < 4; ++r) {
            int t = t0 + 16 * w + hi * 4 + r;
            y[((size_t)(b * T) + t) * 1024 + h * 64 + dt * 16 + lx] =
                f2bf(o_acc[dt][r] * lt[r]);
        }
}

// ----------------------------------------------------------------- launcher
extern "C" void kernel_launch(void* const* d_in, const int* in_sizes, int n_in,
                              void* d_out, int out_size, void* d_ws, size_t ws_size,
                              hipStream_t stream)
{
    const float* x     = (const float*)d_in[0];
    const float* ve    = (const float*)d_in[1];
    const float* cosb  = (const float*)d_in[2];
    const float* sinb  = (const float*)d_in[3];
    const float* Wq    = (const float*)d_in[4];
    const float* Wk    = (const float*)d_in[5];
    const float* Wv    = (const float*)d_in[6];
    const float* Wproj = (const float*)d_in[7];
    const float* Wg    = (const float*)d_in[8];
    const float* memk  = (const float*)d_in[9];
    const float* memv  = (const float*)d_in[10];
    const float* vscal = (const float*)d_in[11];

    unsigned short* xh    = (unsigned short*)d_ws;
    unsigned short* wqkv  = xh + (size_t)4096 * 1024;
    unsigned short* wproj = wqkv + (size_t)1536 * 1024;
    unsigned short* qhb   = wproj + (size_t)1024 * 1024;
    unsigned short* kfull = qhb + (size_t)4096 * 1024;
    unsigned short* vfull = kfull + (size_t)B * NKV * S_TOT * 64;
    unsigned short* qkvb  = vfull + (size_t)B * NKV * S_TOT * 64;  // 4096x1536 bf16
    unsigned short* ybuf  = xh;   // alias: xh dead after QKV GEMM
    float* out = (float*)d_out;

    const dim3 blk(256);
    cast_kernel<<<dim3(4096), blk, 0, stream>>>(x, xh, 1048576);
    cast_kernel<<<dim3(1024), blk, 0, stream>>>(Wq, wqkv, 262144);
    cast_kernel<<<dim3(256),  blk, 0, stream>>>(Wk, wqkv + (size_t)1024 * 1024, 65536);
    cast_kernel<<<dim3(256),  blk, 0, stream>>>(Wv, wqkv + (size_t)1280 * 1024, 65536);
    cast_kernel<<<dim3(1024), blk, 0, stream>>>(Wproj, wproj, 262144);

    gemm_bf16<true><<<dim3(12, 32), blk, 0, stream>>>(xh, wqkv, qkvb, 1536, 1024);
    fuse_kernel<<<dim3(B * T), blk, 0, stream>>>(x, ve, cosb, sinb, Wg, qkvb,
                                                 qhb, kfull, vfull);
    mem_kernel<<<dim3(B * M), blk, 0, stream>>>(memk, memv, vscal, kfull, vfull);
    attn_kernel<<<dim3(T / 64, NH, B), blk, 0, stream>>>(qhb, kfull, vfull, ybuf);
    // proj: output is 4096 x 1024 -> Nn = 1024 (R3 bug: was 4096 -> OOB on d_out)
    gemm_bf16<false><<<dim3(8, 32), blk, 0, stream>>>(ybuf, wproj, out, 1024, 1024);
}

// Round 5
// 192.113 us; speedup vs baseline: 1.2259x; 1.2259x over previous
//
#include <hip/hip_runtime.h>
#include <hip/hip_bf16.h>
#include <math.h>

#define B 2
#define T 2048
#define C 1024
#define NH 16
#define NKV 4
#define HD 64
#define M 64
#define GC 32
#define S_TOT (M + T)   // 2112
#define EPS 1e-6f

using bf16x8  = __attribute__((ext_vector_type(8))) __bf16;
using f32x4   = __attribute__((ext_vector_type(4))) float;
using ushort8 = __attribute__((ext_vector_type(8))) unsigned short;
using ushort4v= __attribute__((ext_vector_type(4))) unsigned short;

typedef __attribute__((address_space(1))) const void GV;
typedef __attribute__((address_space(3))) void LV;

__device__ inline unsigned short f2bf(float f) {
    __bf16 h = (__bf16)f;
    return __builtin_bit_cast(unsigned short, h);
}
__device__ inline float bf2f(unsigned short u) {
    unsigned int x = (unsigned int)u << 16;
    return __builtin_bit_cast(float, x);
}
__device__ inline float wave_sum(float v) {
    #pragma unroll
    for (int off = 32; off; off >>= 1) v += __shfl_xor(v, off, 64);
    return v;
}

// ------------------------------------------------------------ fp32 -> bf16
__global__ __launch_bounds__(256) void cast_kernel(
    const float* __restrict__ src, unsigned short* __restrict__ dst, int n4)
{
    int i = blockIdx.x * 256 + threadIdx.x;
    if (i < n4) {
        float4 v = ((const float4*)src)[i];
        ushort4v o;
        o.x = f2bf(v.x); o.y = f2bf(v.y); o.z = f2bf(v.z); o.w = f2bf(v.w);
        ((ushort4v*)dst)[i] = o;
    }
}

// ------------------------------------------------------- bf16 MFMA GEMM (m97)
template<bool OUT_BF16>
__global__ __launch_bounds__(256) void gemm_bf16(
    const unsigned short* __restrict__ A, const unsigned short* __restrict__ Bt,
    void* __restrict__ Cc, int Nn, int Kk)
{
    __shared__ unsigned short As[128 * 64];
    __shared__ unsigned short Bs[128 * 64];
    const int tid = threadIdx.x;
    const int w = tid >> 6, lane = tid & 63, lx = lane & 15, hi = lane >> 4;
    const int wr = w >> 1, wc = w & 1;
    const int m0 = blockIdx.y * 128, n0 = blockIdx.x * 128;
    const int lrow = lane >> 3;
    const int lcol = (lane & 7) * 8;

    f32x4 acc[4][4];
    #pragma unroll
    for (int mi = 0; mi < 4; ++mi)
        #pragma unroll
        for (int ni = 0; ni < 4; ++ni) acc[mi][ni] = (f32x4){0.f, 0.f, 0.f, 0.f};

    for (int k0 = 0; k0 < Kk; k0 += 64) {
        #pragma unroll
        for (int p = 0; p < 4; ++p) {
            const int chunk = w * 4 + p;
            const int row = chunk * 8 + lrow;
            __builtin_amdgcn_global_load_lds(
                (GV*)(A + (size_t)(m0 + row) * Kk + k0 + lcol),
                (LV*)(As + chunk * 512), 16, 0, 0);
            __builtin_amdgcn_global_load_lds(
                (GV*)(Bt + (size_t)(n0 + row) * Kk + k0 + lcol),
                (LV*)(Bs + chunk * 512), 16, 0, 0);
        }
        __syncthreads();
        #pragma unroll
        for (int kk = 0; kk < 2; ++kk) {
            bf16x8 af[4], bfr[4];
            #pragma unroll
            for (int mi = 0; mi < 4; ++mi)
                af[mi] = *(const bf16x8*)&As[(wr * 64 + mi * 16 + lx) * 64 + kk * 32 + hi * 8];
            #pragma unroll
            for (int ni = 0; ni < 4; ++ni)
                bfr[ni] = *(const bf16x8*)&Bs[(wc * 64 + ni * 16 + lx) * 64 + kk * 32 + hi * 8];
            #pragma unroll
            for (int mi = 0; mi < 4; ++mi)
                #pragma unroll
                for (int ni = 0; ni < 4; ++ni)
                    acc[mi][ni] = __builtin_amdgcn_mfma_f32_16x16x32_bf16(
                        af[mi], bfr[ni], acc[mi][ni], 0, 0, 0);
        }
        __syncthreads();
    }
    #pragma unroll
    for (int mi = 0; mi < 4; ++mi)
        #pragma unroll
        for (int ni = 0; ni < 4; ++ni)
            #pragma unroll
            for (int r = 0; r < 4; ++r) {
                size_t idx = (size_t)(m0 + wr * 64 + mi * 16 + hi * 4 + r) * Nn
                           + n0 + wc * 64 + ni * 16 + lx;
                if constexpr (OUT_BF16) ((unsigned short*)Cc)[idx] = f2bf(acc[mi][ni][r]);
                else                    ((float*)Cc)[idx] = acc[mi][ni][r];
            }
}

// ------------------------------------------------- gate + RoPE + RMS fusion
// q scale folds in 1/sqrt(HD): 1.2 * 0.125 = 0.15
__global__ __launch_bounds__(256) void fuse_kernel(
    const float* __restrict__ x, const float* __restrict__ ve,
    const float* __restrict__ cosb, const float* __restrict__ sinb,
    const float* __restrict__ Wg, const unsigned short* __restrict__ qkv,
    unsigned short* __restrict__ qh, unsigned short* __restrict__ kfull,
    unsigned short* __restrict__ vfull)
{
    const int bt = blockIdx.x;
    const int b = bt >> 11, t = bt & (T - 1);
    const int w = threadIdx.x >> 6, l = threadIdx.x & 63, i = l & 31;
    const float c = cosb[t * 32 + i];
    const float s = sinb[t * 32 + i];
    const unsigned short* row = qkv + (size_t)bt * 1536;

    #pragma unroll
    for (int hq = 0; hq < 4; ++hq) {
        const int h = w + hq * 4;
        float x1 = bf2f(row[h * 64 + i]);
        float x2 = bf2f(row[h * 64 + i + 32]);
        float val = (l < 32) ? (x1 * c - x2 * s) : (x1 * s + x2 * c);
        float ss = wave_sum(val * val);
        float scale = rsqrtf(ss * (1.f / 64.f) + EPS) * 0.15f;
        qh[((size_t)(b * NH + h) * T + t) * 64 + l] = f2bf(val * scale);
    }
    {
        float x1 = bf2f(row[1024 + w * 64 + i]);
        float x2 = bf2f(row[1024 + w * 64 + i + 32]);
        float val = (l < 32) ? (x1 * c - x2 * s) : (x1 * s + x2 * c);
        float ss = wave_sum(val * val);
        float scale = rsqrtf(ss * (1.f / 64.f) + EPS) * 1.2f;
        kfull[((size_t)(b * NKV + w) * S_TOT + M + t) * 64 + l] = f2bf(val * scale);
    }
    {
        const float* xr = x + (size_t)bt * 1024;
        float g = 0.f;
        #pragma unroll
        for (int gi = 0; gi < GC; ++gi) g += xr[gi] * Wg[w * GC + gi];
        g = 3.f / (1.f + __expf(-g));
        float vv = bf2f(row[1280 + w * 64 + l]) + g * ve[(size_t)bt * 256 + w * 64 + l];
        vfull[((size_t)(b * NKV + w) * S_TOT + M + t) * 64 + l] = f2bf(vv);
    }
}

// ------------------------------------------------------- memory token prep
__global__ __launch_bounds__(256) void mem_kernel(
    const float* __restrict__ mem_k, const float* __restrict__ mem_v,
    const float* __restrict__ vscal,
    unsigned short* __restrict__ kfull, unsigned short* __restrict__ vfull)
{
    const int bm = blockIdx.x;
    const int b = bm >> 6, mr = bm & 63;
    const int w = threadIdx.x >> 6, l = threadIdx.x & 63;
    const size_t src = ((size_t)mr * NKV + w) * HD + l;
    float kvv = mem_k[src];
    float ss = wave_sum(kvv * kvv);
    float scale = rsqrtf(ss * (1.f / 64.f) + EPS) * 1.2f;
    const size_t dst = ((size_t)(b * NKV + w) * S_TOT + mr) * 64 + l;
    kfull[dst] = f2bf(kvv * scale);
    vfull[dst] = f2bf(mem_v[src] * vscal[0]);
}

// --------------------------------------------------------- MFMA flash attn v5
// block = (tt, h, b): 128 q-rows, 4 waves, wave w owns rows t0+32w..+31.
// K: async global_load_lds double-buffer, XOR-swizzled via pre-swizzled source.
// V: reg-prefetch -> transposed LDS double-buffer. 1 barrier per tile.
struct AttnShared {
    unsigned short Ks[2][4096];     // [buf][row*64 + swizzled col]
    unsigned short Vt[2][64][72];   // [buf][d][s]
    unsigned short Ps[128][72];     // [qrow][s]
};

__device__ __forceinline__ void attn_tile(
    const int st, const int nst, const int t0, const int w,
    const int lane, const int lx, const int hi,
    const unsigned short* __restrict__ kbase,
    const unsigned short* __restrict__ vbase,
    AttnShared* sh,
    ushort8 (&vn_c)[2], ushort8 (&vn_n)[2],
    const bf16x8 (&aq)[2][2],
    f32x4 (&o_acc)[2][4], float (&m_r)[2][4], float (&l_r)[2][4])
{
    const int cur = st & 1;
    // 1. write prefetched V (tile st) transposed into Vt[cur]
    #pragma unroll
    for (int p = 0; p < 2; ++p) {
        const int kb = p * 4 + w;
        #pragma unroll
        for (int j = 0; j < 8; ++j) sh->Vt[cur][kb * 8 + j][lane] = (unsigned short)vn_c[p][j];
    }
    __syncthreads();   // drains K gload_lds for tile st; publishes Vt[cur]
    // 2. prefetch tile st+1 (hidden under this tile's compute)
    if (st + 1 < nst) {
        const int s0n = (st + 1) * 64;
        const int swz = ((lane & 7) ^ (lane >> 3)) << 3;   // pre-swizzled source
        #pragma unroll
        for (int p = 0; p < 2; ++p) {
            const int chunk = p * 4 + w;
            __builtin_amdgcn_global_load_lds(
                (GV*)(kbase + (size_t)(s0n + chunk * 8 + (lane >> 3)) * 64 + swz),
                (LV*)(&sh->Ks[cur ^ 1][chunk * 512]), 16, 0, 0);
        }
        const unsigned short* vp = vbase + (size_t)(s0n + lane) * 64;
        vn_n[0] = *(const ushort8*)&vp[w * 8];
        vn_n[1] = *(const ushort8*)&vp[(4 + w) * 8];
    }
    // 3. K fragments from Ks[cur] (swizzled read)
    const int r7 = lx & 7;
    const int c0 = (hi ^ r7) << 3;
    const int c1 = ((hi + 4) ^ r7) << 3;
    bf16x8 kb0[4], kb1[4];
    #pragma unroll
    for (int nt = 0; nt < 4; ++nt) {
        const int row = nt * 16 + lx;
        kb0[nt] = *(const bf16x8*)&sh->Ks[cur][row * 64 + c0];
        kb1[nt] = *(const bf16x8*)&sh->Ks[cur][row * 64 + c1];
    }
    // 4. S = Q K^T (scale already folded into q)
    f32x4 s_acc[2][4];
    #pragma unroll
    for (int rb = 0; rb < 2; ++rb)
        #pragma unroll
        for (int nt = 0; nt < 4; ++nt) {
            s_acc[rb][nt] = (f32x4){0.f, 0.f, 0.f, 0.f};
            s_acc[rb][nt] = __builtin_amdgcn_mfma_f32_16x16x32_bf16(aq[rb][0], kb0[nt], s_acc[rb][nt], 0, 0, 0);
            s_acc[rb][nt] = __builtin_amdgcn_mfma_f32_16x16x32_bf16(aq[rb][1], kb1[nt], s_acc[rb][nt], 0, 0, 0);
        }
    // 5. mask + online softmax (mask iff s > t + M, uniform all tiles)
    #pragma unroll
    for (int rb = 0; rb < 2; ++rb) {
        const int rowb = t0 + 32 * w + rb * 16 + hi * 4;
        float mx[4];
        #pragma unroll
        for (int r = 0; r < 4; ++r) {
            const int thr = rowb + r + 64 - 64 * st;
            #pragma unroll
            for (int nt = 0; nt < 4; ++nt)
                if (nt * 16 + lx > thr) s_acc[rb][nt][r] = -INFINITY;
            mx[r] = fmaxf(fmaxf(s_acc[rb][0][r], s_acc[rb][1][r]),
                          fmaxf(s_acc[rb][2][r], s_acc[rb][3][r]));
        }
        #pragma unroll
        for (int off = 1; off < 16; off <<= 1)
            #pragma unroll
            for (int r = 0; r < 4; ++r) mx[r] = fmaxf(mx[r], __shfl_xor(mx[r], off, 64));
        #pragma unroll
        for (int r = 0; r < 4; ++r) {
            const float mn = fmaxf(m_r[rb][r], mx[r]);
            const float resc = __expf(m_r[rb][r] - mn);
            m_r[rb][r] = mn;
            float ps = 0.f;
            #pragma unroll
            for (int nt = 0; nt < 4; ++nt) {
                float p = __expf(s_acc[rb][nt][r] - mn);
                ps += p;
                sh->Ps[w * 32 + rb * 16 + hi * 4 + r][nt * 16 + lx] = f2bf(p);
            }
            l_r[rb][r] = l_r[rb][r] * resc + ps;
            #pragma unroll
            for (int dt = 0; dt < 4; ++dt) o_acc[rb][dt][r] *= resc;
        }
    }
    // 6. O += P V
    #pragma unroll
    for (int kk = 0; kk < 2; ++kk) {
        bf16x8 pa0 = *(const bf16x8*)&sh->Ps[w * 32 + lx][kk * 32 + hi * 8];
        bf16x8 pa1 = *(const bf16x8*)&sh->Ps[w * 32 + 16 + lx][kk * 32 + hi * 8];
        #pragma unroll
        for (int dt = 0; dt < 4; ++dt) {
            bf16x8 vb = *(const bf16x8*)&sh->Vt[cur][dt * 16 + lx][kk * 32 + hi * 8];
            o_acc[0][dt] = __builtin_amdgcn_mfma_f32_16x16x32_bf16(pa0, vb, o_acc[0][dt], 0, 0, 0);
            o_acc[1][dt] = __builtin_amdgcn_mfma_f32_16x16x32_bf16(pa1, vb, o_acc[1][dt], 0, 0, 0);
        }
    }
}

__global__ __launch_bounds__(256) void attn_kernel(
    const unsigned short* __restrict__ qh, const unsigned short* __restrict__ kf,
    const unsigned short* __restrict__ vf, unsigned short* __restrict__ y)
{
    __shared__ AttnShared sh;
    const int tt = (T / 128 - 1) - blockIdx.x;   // long blocks launch first
    const int h = blockIdx.y, b = blockIdx.z;
    const int kv = h >> 2, t0 = tt * 128;
    const int tid = threadIdx.x, w = tid >> 6, lane = tid & 63;
    const int lx = lane & 15, hi = lane >> 4;

    bf16x8 aq[2][2];
    #pragma unroll
    for (int rb = 0; rb < 2; ++rb) {
        const unsigned short* qp = qh + ((size_t)(b * NH + h) * T + t0 + 32 * w + rb * 16 + lx) * 64;
        aq[rb][0] = *(const bf16x8*)&qp[hi * 8];
        aq[rb][1] = *(const bf16x8*)&qp[32 + hi * 8];
    }
    f32x4 o_acc[2][4];
    float m_r[2][4], l_r[2][4];
    #pragma unroll
    for (int rb = 0; rb < 2; ++rb)
        #pragma unroll
        for (int dt = 0; dt < 4; ++dt) o_acc[rb][dt] = (f32x4){0.f, 0.f, 0.f, 0.f};
    #pragma unroll
    for (int rb = 0; rb < 2; ++rb)
        #pragma unroll
        for (int r = 0; r < 4; ++r) { m_r[rb][r] = -INFINITY; l_r[rb][r] = 0.f; }

    const unsigned short* kbase = kf + (size_t)(b * NKV + kv) * S_TOT * 64;
    const unsigned short* vbase = vf + (size_t)(b * NKV + kv) * S_TOT * 64;

    const int nst = 2 * tt + 3;   // always odd
    // prologue: stage K tile 0 -> Ks[0]; V tile 0 -> regs
    {
        const int swz = ((lane & 7) ^ (lane >> 3)) << 3;
        #pragma unroll
        for (int p = 0; p < 2; ++p) {
            const int chunk = p * 4 + w;
            __builtin_amdgcn_global_load_lds(
                (GV*)(kbase + (size_t)(chunk * 8 + (lane >> 3)) * 64 + swz),
                (LV*)(&sh.Ks[0][chunk * 512]), 16, 0, 0);
        }
    }
    ushort8 vnA[2], vnB[2];
    {
        const unsigned short* vp = vbase + (size_t)lane * 64;
        vnA[0] = *(const ushort8*)&vp[w * 8];
        vnA[1] = *(const ushort8*)&vp[(4 + w) * 8];
    }
    for (int st = 0; st < nst; st += 2) {
        attn_tile(st, nst, t0, w, lane, lx, hi, kbase, vbase, &sh,
                  vnA, vnB, aq, o_acc, m_r, l_r);
        if (st + 1 < nst)
            attn_tile(st + 1, nst, t0, w, lane, lx, hi, kbase, vbase, &sh,
                      vnB, vnA, aq, o_acc, m_r, l_r);
    }

    #pragma unroll
    for (int rb = 0; rb < 2; ++rb) {
        float lt[4];
        #pragma unroll
        for (int r = 0; r < 4; ++r) {
            float v = l_r[rb][r];
            #pragma unroll
            for (int off = 1; off < 16; off <<= 1) v += __shfl_xor(v, off, 64);
            lt[r] = 1.f / v;
        }
        #pragma unroll
        for (int dt = 0; dt < 4; ++dt)
            #pragma unroll
            for (int r = 0; r < 4; ++r) {
                int t = t0 + 32 * w + rb * 16 + hi * 4 + r;
                y[((size_t)(b * T) + t) * 1024 + h * 64 + dt * 16 + lx] =
                    f2bf(o_acc[rb][dt][r] * lt[r]);
            }
    }
}

// ----------------------------------------------------------------- launcher
extern "C" void kernel_launch(void* const* d_in, const int* in_sizes, int n_in,
                              void* d_out, int out_size, void* d_ws, size_t ws_size,
                              hipStream_t stream)
{
    const float* x     = (const float*)d_in[0];
    const float* ve    = (const float*)d_in[1];
    const float* cosb  = (const float*)d_in[2];
    const float* sinb  = (const float*)d_in[3];
    const float* Wq    = (const float*)d_in[4];
    const float* Wk    = (const float*)d_in[5];
    const float* Wv    = (const float*)d_in[6];
    const float* Wproj = (const float*)d_in[7];
    const float* Wg    = (const float*)d_in[8];
    const float* memk  = (const float*)d_in[9];
    const float* memv  = (const float*)d_in[10];
    const float* vscal = (const float*)d_in[11];

    unsigned short* xh    = (unsigned short*)d_ws;
    unsigned short* wqkv  = xh + (size_t)4096 * 1024;
    unsigned short* wproj = wqkv + (size_t)1536 * 1024;
    unsigned short* qhb   = wproj + (size_t)1024 * 1024;
    unsigned short* kfull = qhb + (size_t)4096 * 1024;
    unsigned short* vfull = kfull + (size_t)B * NKV * S_TOT * 64;
    unsigned short* qkvb  = vfull + (size_t)B * NKV * S_TOT * 64;
    unsigned short* ybuf  = xh;   // alias: xh dead after QKV GEMM
    float* out = (float*)d_out;

    const dim3 blk(256);
    cast_kernel<<<dim3(4096), blk, 0, stream>>>(x, xh, 1048576);
    cast_kernel<<<dim3(1024), blk, 0, stream>>>(Wq, wqkv, 262144);
    cast_kernel<<<dim3(256),  blk, 0, stream>>>(Wk, wqkv + (size_t)1024 * 1024, 65536);
    cast_kernel<<<dim3(256),  blk, 0, stream>>>(Wv, wqkv + (size_t)1280 * 1024, 65536);
    cast_kernel<<<dim3(1024), blk, 0, stream>>>(Wproj, wproj, 262144);

    gemm_bf16<true><<<dim3(12, 32), blk, 0, stream>>>(xh, wqkv, qkvb, 1536, 1024);
    fuse_kernel<<<dim3(B * T), blk, 0, stream>>>(x, ve, cosb, sinb, Wg, qkvb,
                                                 qhb, kfull, vfull);
    mem_kernel<<<dim3(B * M), blk, 0, stream>>>(memk, memv, vscal, kfull, vfull);
    attn_kernel<<<dim3(T / 128, NH, B), blk, 0, stream>>>(qhb, kfull, vfull, ybuf);
    gemm_bf16<false><<<dim3(8, 32), blk, 0, stream>>>(ybuf, wproj, out, 1024, 1024);
}